// Round 5
// baseline (239.694 us; speedup 1.0000x reference)
//
#include <hip/hip_runtime.h>

// ButterflyLinear: N=4096, DEPTH=12, TOKENS=8192, fp32.
// Structure (verified R0): all 12 stages act within aligned float4 groups ->
// network == block-diagonal 1024 x (4x4) linear map.
// R5: back to two kernels (R4 showed fused re-compose costs ~8us in L2
// traffic). Apply kernel now uses an explicit 8-deep rolling load window so
// ~8 float4 loads stay in flight per wave (latency-hiding was the R3 deficit:
// ~4.3 TB/s vs 6.3 TB/s copy ceiling).

#define NFEAT   4096
#define DEPTH   12
#define NPAIR   (NFEAT / 2)
#define NGROUPS (NFEAT / 4)      // 1024
#define TOKENS  8192
#define GBLK    256
#define TOK_PER_BLK 16
#define PF      8                // rolling prefetch depth (power of two)

typedef float fx4 __attribute__((ext_vector_type(4)));

__device__ __forceinline__ float4 stage0_apply(float4 v, float4 a, float4 b) {
    // pairs (v0,v1) w/ a, (v2,v3) w/ b
    return make_float4(v.x * a.x + v.y * a.z,
                       v.x * a.y + v.y * a.w,
                       v.z * b.x + v.w * b.z,
                       v.z * b.y + v.w * b.w);
}
__device__ __forceinline__ float4 stageS_apply(float4 v, float4 a, float4 b) {
    // pairs (v0,v2) w/ a, (v1,v3) w/ b
    return make_float4(v.x * a.x + v.z * a.z,
                       v.y * b.x + v.w * b.z,
                       v.x * a.y + v.z * a.w,
                       v.y * b.y + v.w * b.w);
}

// ---- kernel 1: compose the 4x4 map per group (4 column vectors) ----
__global__ __launch_bounds__(256)
void compose_kernel(const float* __restrict__ factors, float* __restrict__ M)
{
    const int k = blockIdx.x * 256 + threadIdx.x;   // group 0..1023

    float4 c0 = make_float4(1.f, 0.f, 0.f, 0.f);
    float4 c1 = make_float4(0.f, 1.f, 0.f, 0.f);
    float4 c2 = make_float4(0.f, 0.f, 1.f, 0.f);
    float4 c3 = make_float4(0.f, 0.f, 0.f, 1.f);

    {   // stage 0: factors 2k, 2k+1
        const float4 a = *(const float4*)(factors + (size_t)(2 * k    ) * 4);
        const float4 b = *(const float4*)(factors + (size_t)(2 * k + 1) * 4);
        c0 = stage0_apply(c0, a, b);
        c1 = stage0_apply(c1, a, b);
        c2 = stage0_apply(c2, a, b);
        c3 = stage0_apply(c3, a, b);
    }
#pragma unroll
    for (int s = 1; s < DEPTH; ++s) {
        const int lowmask = (1 << (s - 1)) - 1;
        const int p0 = ((k >> (s - 1)) << s) | (k & lowmask);
        const int p1 = p0 + (1 << (s - 1));
        const float4 a = *(const float4*)(factors + (size_t)(s * NPAIR + p0) * 4);
        const float4 b = *(const float4*)(factors + (size_t)(s * NPAIR + p1) * 4);
        c0 = stageS_apply(c0, a, b);
        c1 = stageS_apply(c1, a, b);
        c2 = stageS_apply(c2, a, b);
        c3 = stageS_apply(c3, a, b);
    }

    float4* m = (float4*)(M + (size_t)k * 16);
    m[0] = c0; m[1] = c1; m[2] = c2; m[3] = c3;
}

// ---- kernel 2: out[b] = M_k * x[b] + bias, rolling 8-deep pipeline ----
__global__ __launch_bounds__(GBLK)
void apply_kernel(const float* __restrict__ x,
                  const float* __restrict__ M,
                  const float* __restrict__ bias,
                  float* __restrict__ out)
{
    const int k    = blockIdx.x * GBLK + threadIdx.x;   // group 0..1023
    const int tok0 = blockIdx.y * TOK_PER_BLK;

    const fx4* mp = (const fx4*)(M + (size_t)k * 16);
    const fx4 c0 = mp[0], c1 = mp[1], c2 = mp[2], c3 = mp[3];
    const fx4 bv = *(const fx4*)(bias + 4 * k);

    const float* xp = x   + (size_t)tok0 * NFEAT + 4 * k;
    float*       op = out + (size_t)tok0 * NFEAT + 4 * k;

    fx4 v[PF];
#pragma unroll
    for (int t = 0; t < PF; ++t)
        v[t] = __builtin_nontemporal_load((const fx4*)(xp + (size_t)t * NFEAT));

#pragma unroll
    for (int t = 0; t < TOK_PER_BLK; ++t) {
        const fx4 cur = v[t & (PF - 1)];               // static index (unrolled)
        if (t + PF < TOK_PER_BLK)
            v[t & (PF - 1)] = __builtin_nontemporal_load(
                (const fx4*)(xp + (size_t)(t + PF) * NFEAT));
        fx4 r;
        r.x = bv.x + cur.x * c0.x + cur.y * c1.x + cur.z * c2.x + cur.w * c3.x;
        r.y = bv.y + cur.x * c0.y + cur.y * c1.y + cur.z * c2.y + cur.w * c3.y;
        r.z = bv.z + cur.x * c0.z + cur.y * c1.z + cur.z * c2.z + cur.w * c3.z;
        r.w = bv.w + cur.x * c0.w + cur.y * c1.w + cur.z * c2.w + cur.w * c3.w;
        __builtin_nontemporal_store(r, (fx4*)(op + (size_t)t * NFEAT));
    }
}

extern "C" void kernel_launch(void* const* d_in, const int* in_sizes, int n_in,
                              void* d_out, int out_size, void* d_ws, size_t ws_size,
                              hipStream_t stream) {
    const float* x       = (const float*)d_in[0];
    const float* factors = (const float*)d_in[1];
    const float* bias    = (const float*)d_in[2];
    float* out           = (float*)d_out;
    float* M             = (float*)d_ws;    // 1024 * 16 floats = 64 KB

    compose_kernel<<<dim3(NGROUPS / 256), dim3(256), 0, stream>>>(factors, M);

    dim3 grid(NGROUPS / GBLK, TOKENS / TOK_PER_BLK);   // (4, 512) = 2048 blocks
    apply_kernel<<<grid, dim3(GBLK), 0, stream>>>(x, M, bias, out);
}

// Round 6
// 232.483 us; speedup vs baseline: 1.0310x; 1.0310x over previous
//
#include <hip/hip_runtime.h>

// ButterflyLinear: N=4096, DEPTH=12, TOKENS=8192, fp32.
// Structure (verified R0): all 12 stages act within aligned float4 groups ->
// network == block-diagonal 1024 x (4x4) linear map.
// R6: exact R3 two-kernel structure, but with nontemporal hints REMOVED.
// Rationale: x is L3-resident after the harness's input-restore copy (R0
// showed FETCH_SIZE 64MiB < |x| = 134MiB), and plain fills stream at 6.7
// TB/s; nt-flagged loads/stores forfeit L3 hits / early-evict. Clean A/B
// vs R3 (228.5us total, apply ~68us).

#define NFEAT   4096
#define DEPTH   12
#define NPAIR   (NFEAT / 2)
#define NGROUPS (NFEAT / 4)      // 1024
#define TOKENS  8192
#define GBLK    256
#define TOK_PER_BLK 8

typedef float fx4 __attribute__((ext_vector_type(4)));

__device__ __forceinline__ float4 stage0_apply(float4 v, float4 a, float4 b) {
    // pairs (v0,v1) w/ a, (v2,v3) w/ b
    return make_float4(v.x * a.x + v.y * a.z,
                       v.x * a.y + v.y * a.w,
                       v.z * b.x + v.w * b.z,
                       v.z * b.y + v.w * b.w);
}
__device__ __forceinline__ float4 stageS_apply(float4 v, float4 a, float4 b) {
    // pairs (v0,v2) w/ a, (v1,v3) w/ b
    return make_float4(v.x * a.x + v.z * a.z,
                       v.y * b.x + v.w * b.z,
                       v.x * a.y + v.z * a.w,
                       v.y * b.y + v.w * b.w);
}

// ---- kernel 1: compose the 4x4 map per group (4 column vectors) ----
__global__ __launch_bounds__(256)
void compose_kernel(const float* __restrict__ factors, float* __restrict__ M)
{
    const int k = blockIdx.x * 256 + threadIdx.x;   // group 0..1023

    float4 c0 = make_float4(1.f, 0.f, 0.f, 0.f);
    float4 c1 = make_float4(0.f, 1.f, 0.f, 0.f);
    float4 c2 = make_float4(0.f, 0.f, 1.f, 0.f);
    float4 c3 = make_float4(0.f, 0.f, 0.f, 1.f);

    {   // stage 0: factors 2k, 2k+1
        const float4 a = *(const float4*)(factors + (size_t)(2 * k    ) * 4);
        const float4 b = *(const float4*)(factors + (size_t)(2 * k + 1) * 4);
        c0 = stage0_apply(c0, a, b);
        c1 = stage0_apply(c1, a, b);
        c2 = stage0_apply(c2, a, b);
        c3 = stage0_apply(c3, a, b);
    }
#pragma unroll
    for (int s = 1; s < DEPTH; ++s) {
        const int lowmask = (1 << (s - 1)) - 1;
        const int p0 = ((k >> (s - 1)) << s) | (k & lowmask);
        const int p1 = p0 + (1 << (s - 1));
        const float4 a = *(const float4*)(factors + (size_t)(s * NPAIR + p0) * 4);
        const float4 b = *(const float4*)(factors + (size_t)(s * NPAIR + p1) * 4);
        c0 = stageS_apply(c0, a, b);
        c1 = stageS_apply(c1, a, b);
        c2 = stageS_apply(c2, a, b);
        c3 = stageS_apply(c3, a, b);
    }

    float4* m = (float4*)(M + (size_t)k * 16);
    m[0] = c0; m[1] = c1; m[2] = c2; m[3] = c3;
}

// ---- kernel 2: out[b] = M_k * x[b] + bias, plain cached loads/stores ----
__global__ __launch_bounds__(GBLK)
void apply_kernel(const float* __restrict__ x,
                  const float* __restrict__ M,
                  const float* __restrict__ bias,
                  float* __restrict__ out)
{
    const int k    = blockIdx.x * GBLK + threadIdx.x;   // group 0..1023
    const int tok0 = blockIdx.y * TOK_PER_BLK;

    const fx4* mp = (const fx4*)(M + (size_t)k * 16);
    const fx4 c0 = mp[0], c1 = mp[1], c2 = mp[2], c3 = mp[3];
    const fx4 bv = *(const fx4*)(bias + 4 * k);

    const float* xp = x   + (size_t)tok0 * NFEAT + 4 * k;
    float*       op = out + (size_t)tok0 * NFEAT + 4 * k;

#pragma unroll
    for (int t = 0; t < TOK_PER_BLK; ++t) {
        const fx4 v = *(const fx4*)(xp + (size_t)t * NFEAT);
        fx4 r;
        r.x = bv.x + v.x * c0.x + v.y * c1.x + v.z * c2.x + v.w * c3.x;
        r.y = bv.y + v.x * c0.y + v.y * c1.y + v.z * c2.y + v.w * c3.y;
        r.z = bv.z + v.x * c0.z + v.y * c1.z + v.z * c2.z + v.w * c3.z;
        r.w = bv.w + v.x * c0.w + v.y * c1.w + v.z * c2.w + v.w * c3.w;
        *(fx4*)(op + (size_t)t * NFEAT) = r;
    }
}

extern "C" void kernel_launch(void* const* d_in, const int* in_sizes, int n_in,
                              void* d_out, int out_size, void* d_ws, size_t ws_size,
                              hipStream_t stream) {
    const float* x       = (const float*)d_in[0];
    const float* factors = (const float*)d_in[1];
    const float* bias    = (const float*)d_in[2];
    float* out           = (float*)d_out;
    float* M             = (float*)d_ws;    // 1024 * 16 floats = 64 KB

    compose_kernel<<<dim3(NGROUPS / 256), dim3(256), 0, stream>>>(factors, M);

    dim3 grid(NGROUPS / GBLK, TOKENS / TOK_PER_BLK);   // (4, 1024) = 4096 blocks
    apply_kernel<<<grid, dim3(GBLK), 0, stream>>>(x, M, bias, out);
}